// Round 12
// baseline (606.003 us; speedup 1.0000x reference)
//
#include <hip/hip_runtime.h>
#include <hip/hip_bf16.h>

static constexpr int NF   = 50;   // input features
static constexpr int C1   = 64;   // conv1/conv2 channels
static constexpr int OUTF = 16;   // final output features
static constexpr int SCAN_T = 256;
static constexpr int SCAN_I = 4;
static constexpr float DEG_SCALE   = 8388608.f;      // 2^23 fixed-point for packed deg
static constexpr float DEG_INV     = 1.f / 8388608.f;

// ---------------------------------------------------------------- CSR build
// ONE packed 64-bit atomic per edge: high word = edge count, low word = fixed-point
// weighted degree. Returned old high word = this edge's rank within its row.
__global__ void pass1_kernel(const int* __restrict__ row, const float* __restrict__ w,
                             unsigned long long* __restrict__ pcd, int* __restrict__ rank, int e)
{
    int i = blockIdx.x * blockDim.x + threadIdx.x;
    if (i < e) {
        int r = row[i];
        unsigned int wq = (unsigned int)(w[i] * DEG_SCALE + 0.5f);
        unsigned long long pk = (1ULL << 32) | (unsigned long long)wq;
        unsigned long long old = atomicAdd(&pcd[r], pk);
        rank[i] = (int)(old >> 32);
    }
}

__global__ void dis_kernel(const unsigned long long* __restrict__ pcd,
                           float* __restrict__ dis, int* __restrict__ cnt, int n)
{
    int i = blockIdx.x * blockDim.x + threadIdx.x;
    if (i < n) {
        unsigned long long pk = pcd[i];
        int c = (int)(pk >> 32);
        float d = (float)(unsigned int)(pk & 0xFFFFFFFFu) * DEG_INV;
        cnt[i] = c;
        dis[i] = (d > 0.f) ? (1.f / sqrtf(d)) : 0.f;
    }
}

__global__ void scan_partial(const int* __restrict__ cnt, int* __restrict__ bsum, int n)
{
    __shared__ int sm[SCAN_T];
    int t = threadIdx.x;
    int base = blockIdx.x * SCAN_T * SCAN_I + t * SCAN_I;
    int s = 0;
    #pragma unroll
    for (int k = 0; k < SCAN_I; ++k) { int i = base + k; if (i < n) s += cnt[i]; }
    sm[t] = s; __syncthreads();
    for (int off = SCAN_T / 2; off > 0; off >>= 1) {
        if (t < off) sm[t] += sm[t + off];
        __syncthreads();
    }
    if (t == 0) bsum[blockIdx.x] = sm[0];
}

// single block; requires nb <= 256 (here nb = 98)
__global__ void scan_bsums(int* __restrict__ bsum, int nb)
{
    __shared__ int sm[256];
    int t = threadIdx.x;
    sm[t] = (t < nb) ? bsum[t] : 0;
    __syncthreads();
    for (int off = 1; off < 256; off <<= 1) {
        int v = (t >= off) ? sm[t - off] : 0;
        __syncthreads();
        sm[t] += v;
        __syncthreads();
    }
    if (t < nb) bsum[t] = (t == 0) ? 0 : sm[t - 1];   // exclusive
}

__global__ void scan_final(const int* __restrict__ cnt, const int* __restrict__ bsum,
                           int* __restrict__ rowptr, int n)
{
    __shared__ int sm[SCAN_T];
    int t = threadIdx.x;
    int base = blockIdx.x * SCAN_T * SCAN_I + t * SCAN_I;
    int v[SCAN_I]; int s = 0;
    #pragma unroll
    for (int k = 0; k < SCAN_I; ++k) { int i = base + k; v[k] = (i < n) ? cnt[i] : 0; s += v[k]; }
    sm[t] = s; __syncthreads();
    for (int off = 1; off < SCAN_T; off <<= 1) {
        int x = (t >= off) ? sm[t - off] : 0;
        __syncthreads();
        sm[t] += x;
        __syncthreads();
    }
    int pref = bsum[blockIdx.x] + sm[t] - s;   // thread-exclusive prefix
    #pragma unroll
    for (int k = 0; k < SCAN_I; ++k) {
        int i = base + k;
        if (i < n) { rowptr[i] = pref; pref += v[k]; }
    }
}

// atomic-free scatter: pos = rowptr[row] + rank. Writes interleaved (col, norm) int2.
__global__ void scatter_kernel(const int* __restrict__ row, const int* __restrict__ col,
                               const float* __restrict__ w, const float* __restrict__ dis,
                               const int* __restrict__ rowptr, const int* __restrict__ rank,
                               int2* __restrict__ ecn, int e)
{
    int i = blockIdx.x * blockDim.x + threadIdx.x;
    if (i < e) {
        int r = row[i], c = col[i];
        int pos = rowptr[r] + rank[i];
        float nv = -dis[r] * w[i] * dis[c];
        ecn[pos] = make_int2(c, __float_as_int(nv));
    }
}

// pad x [n][50] -> X64 [n][64] (zeros beyond 50) so all gather tables are float4 stride-64
__global__ void padx_kernel(const float* __restrict__ x, float4* __restrict__ X4, int n16)
{
    int i = blockIdx.x * blockDim.x + threadIdx.x;
    if (i < n16) {
        int row = i >> 4, f0 = (i & 15) * 4;
        float4 v;
        v.x = (f0 + 0 < NF) ? x[row * NF + f0 + 0] : 0.f;
        v.y = (f0 + 1 < NF) ? x[row * NF + f0 + 1] : 0.f;
        v.z = (f0 + 2 < NF) ? x[row * NF + f0 + 2] : 0.f;
        v.w = (f0 + 3 < NF) ? x[row * NF + f0 + 3] : 0.f;
        X4[i] = v;
    }
}

// ---------------------------------------------------------------- propagate (pure gather)
// One wave per row. lane = (edge_slot sub=lane>>4, feature_quad f4=lane&15):
// one gather instruction serves 4 edges x 16B = 4 full rows -> 4x fewer VMEM
// instructions, 4x more bytes in flight (8 instrs x 64 lanes x 16B = 8KB/wave).
// Cross-edge reduce via shfl_xor(32,16); lanes 0-15 write the 256B row.
// All tables stride-64 float4. BS>0: fuse T2 = 2*acc - base[row].
template<int BS>
__global__ __launch_bounds__(256) void prop_kernel(
    const float* __restrict__ xin, const float* __restrict__ base,
    const int* __restrict__ rowptr, const int* __restrict__ cnt,
    const int2* __restrict__ ecn, float* __restrict__ yout, int n)
{
    int gw = (blockIdx.x * blockDim.x + threadIdx.x) >> 6;
    int lane = threadIdx.x & 63;
    if (gw >= n) return;
    int st = __builtin_amdgcn_readfirstlane(rowptr[gw]);
    int m  = __builtin_amdgcn_readfirstlane(cnt[gw]);
    const int sub = lane >> 4;
    const int f4  = lane & 15;
    const float4* XG = (const float4*)xin;

    float4 a[8];
    #pragma unroll
    for (int k = 0; k < 8; ++k) a[k] = make_float4(0.f, 0.f, 0.f, 0.f);

    for (int t = 0; t < m; t += 32) {          // 32 edges (8 instrs) per round-trip
        #pragma unroll
        for (int k = 0; k < 8; ++k) {
            int e   = t + 4 * k + sub;
            int idx = st + min(e, m - 1);      // clamped: valid when m>=1 (loop guard)
            int2 md = ecn[idx];
            float nv = (e < m) ? __int_as_float(md.y) : 0.f;
            float4 g = XG[md.x * 16 + f4];
            a[k].x = fmaf(nv, g.x, a[k].x);
            a[k].y = fmaf(nv, g.y, a[k].y);
            a[k].z = fmaf(nv, g.z, a[k].z);
            a[k].w = fmaf(nv, g.w, a[k].w);
        }
    }
    float4 av;
    av.x = ((a[0].x + a[1].x) + (a[2].x + a[3].x)) + ((a[4].x + a[5].x) + (a[6].x + a[7].x));
    av.y = ((a[0].y + a[1].y) + (a[2].y + a[3].y)) + ((a[4].y + a[5].y) + (a[6].y + a[7].y));
    av.z = ((a[0].z + a[1].z) + (a[2].z + a[3].z)) + ((a[4].z + a[5].z) + (a[6].z + a[7].z));
    av.w = ((a[0].w + a[1].w) + (a[2].w + a[3].w)) + ((a[4].w + a[5].w) + (a[6].w + a[7].w));
    // reduce over the 4 edge slots (lanes l, l^16, l^32, l^48)
    av.x += __shfl_xor(av.x, 32); av.x += __shfl_xor(av.x, 16);
    av.y += __shfl_xor(av.y, 32); av.y += __shfl_xor(av.y, 16);
    av.z += __shfl_xor(av.z, 32); av.z += __shfl_xor(av.z, 16);
    av.w += __shfl_xor(av.w, 32); av.w += __shfl_xor(av.w, 16);

    if (lane < 16) {
        float4 r = av;
        if (BS > 0) {   // T2 = 2*prop - base  (m==0: -base, correct)
            float4 b = ((const float4*)base)[(size_t)gw * 16 + lane];
            r.x = 2.f * r.x - b.x;
            r.y = 2.f * r.y - b.y;
            r.z = 2.f * r.z - b.z;
            r.w = 2.f * r.w - b.w;
        }
        ((float4*)yout)[(size_t)gw * 16 + lane] = r;   // 256B contiguous
    }
}

// ---------------------------------------------------------------- dense conv1 (+BN stats)
// h = relu(x@W0 + T1@W1 + T2@W2 + b1); h IN PLACE over T1 (row-local).
// Measured-best structure (R9): W in LDS [tap][f/4][j][4]; rows staged coalesced in
// per-wave LDS, read back as same-address b128 broadcasts.
__global__ __launch_bounds__(512) void dense1_kernel(
    const float* __restrict__ x, float* U /*T1 in, h out*/, const float* __restrict__ T2,
    const float* __restrict__ W1, const float* __restrict__ b1,
    float* __restrict__ stats, int n)
{
    __shared__ __align__(16) float WI[3 * 13 * 64 * 4];   // 39936 B
    __shared__ __align__(16) float ROWS[8 * 4 * 3 * 64];  // 24576 B
    __shared__ float red[2][8][64];                       // 4 KB
    const int tid = threadIdx.x;
    for (int i = tid; i < 3 * 13 * 64 * 4; i += 512) WI[i] = 0.f;
    __syncthreads();
    for (int i = tid; i < 3 * NF * C1; i += 512) {
        int tap = i / (NF * C1), rem = i % (NF * C1), f = rem / C1, j = rem % C1;
        WI[((tap * 13 + (f >> 2)) * 64 + j) * 4 + (f & 3)] = W1[i];
    }
    __syncthreads();

    const int lane = tid & 63;
    const int wv   = tid >> 6;
    const int gw   = blockIdx.x * 8 + wv;
    const int rstep = gridDim.x * 8 * 4;
    const float bias = b1[lane];
    const float4* W4 = (const float4*)WI;
    const float4* R4 = (const float4*)ROWS;
    float ssum = 0.f, ssq = 0.f;

    for (int r0 = gw * 4; r0 < n; r0 += rstep) {
        const int nr = min(4, n - r0);
        // stage this wave's 4 rows x 3 tables (coalesced); same-wave use, no barrier
        #pragma unroll
        for (int r = 0; r < 4; ++r) {
            int row = min(r0 + r, n - 1);
            ROWS[((wv * 4 + r) * 3 + 0) * 64 + lane] = (lane < NF) ? x[row * NF + lane] : 0.f;
            ROWS[((wv * 4 + r) * 3 + 1) * 64 + lane] = U [row * C1 + lane];
            ROWS[((wv * 4 + r) * 3 + 2) * 64 + lane] = T2[row * C1 + lane];
        }
        float acc[4] = {bias, bias, bias, bias};
        for (int c = 0; c < 13; ++c) {
            float4 w0 = W4[(0 * 13 + c) * 64 + lane];
            float4 w1 = W4[(1 * 13 + c) * 64 + lane];
            float4 w2 = W4[(2 * 13 + c) * 64 + lane];
            #pragma unroll
            for (int r = 0; r < 4; ++r) {
                float4 t0 = R4[((wv * 4 + r) * 3 + 0) * 16 + c];   // broadcast
                float4 t1 = R4[((wv * 4 + r) * 3 + 1) * 16 + c];
                float4 t2 = R4[((wv * 4 + r) * 3 + 2) * 16 + c];
                acc[r] += t0.x * w0.x + t0.y * w0.y + t0.z * w0.z + t0.w * w0.w
                        + t1.x * w1.x + t1.y * w1.y + t1.z * w1.z + t1.w * w1.w
                        + t2.x * w2.x + t2.y * w2.y + t2.z * w2.z + t2.w * w2.w;
            }
        }
        #pragma unroll
        for (int r = 0; r < 4; ++r) {
            if (r < nr) {
                float v = fmaxf(acc[r], 0.f);
                U[(r0 + r) * C1 + lane] = v;       // in-place: own rows only
                ssum += v; ssq += v * v;
            }
        }
    }
    red[0][wv][lane] = ssum;
    red[1][wv][lane] = ssq;
    __syncthreads();
    if (tid < 128) {
        int which = tid >> 6, j = tid & 63;
        float tot = 0.f;
        #pragma unroll
        for (int wq = 0; wq < 8; ++wq) tot += red[which][wq][j];
        atomicAdd(&stats[which * 64 + j], tot);
    }
}

// ---------------------------------------------------------------- batch norm
__global__ void bn_finalize_kernel(float* __restrict__ stats, const float* __restrict__ gamma,
                                   const float* __restrict__ beta, float inv_n)
{
    int j = threadIdx.x;
    if (j < 64) {
        float mu   = stats[j] * inv_n;
        float var  = stats[64 + j] * inv_n - mu * mu;
        float rstd = 1.f / sqrtf(var + 1e-5f);
        float sc   = gamma[j] * rstd;
        stats[128 + j] = sc;
        stats[192 + j] = beta[j] - mu * sc;
    }
}

__global__ void bn_apply_kernel(float* __restrict__ h, const float* __restrict__ stats, int n4)
{
    int i = blockIdx.x * blockDim.x + threadIdx.x;
    const int stride = gridDim.x * blockDim.x;      // multiple of 16 -> j0 invariant
    int j0 = (i * 4) & 63;
    float s0 = stats[128 + j0], s1 = stats[129 + j0], s2 = stats[130 + j0], s3 = stats[131 + j0];
    float b0 = stats[192 + j0], b1 = stats[193 + j0], b2 = stats[194 + j0], b3 = stats[195 + j0];
    float4* h4 = (float4*)h;
    for (; i < n4; i += stride) {
        float4 v = h4[i];
        v.x = v.x * s0 + b0;
        v.y = v.y * s1 + b1;
        v.z = v.z * s2 + b2;
        v.w = v.w * s3 + b3;
        h4[i] = v;
    }
}

// ---------------------------------------------------------------- dense conv2 + final linear
// g = relu(hb@W0 + Q1@W1 + T2'@W2 + b2);  out = g @ linW^T + linb
__global__ __launch_bounds__(512) void dense2_kernel(
    const float* __restrict__ hb, const float* __restrict__ Q1, const float* __restrict__ T2,
    const float* __restrict__ W2, const float* __restrict__ b2,
    const float* __restrict__ linW, const float* __restrict__ linb,
    float* __restrict__ out, int n)
{
    __shared__ __align__(16) float WI[3 * 16 * 64 * 4];   // 49152 B
    __shared__ __align__(16) float ROWS[8 * 4 * 3 * 64];  // 24576 B (gbuf reuses per-wave slice)
    __shared__ float LWT[C1 * OUTF];                      // 4 KB, [j][o]
    const int tid = threadIdx.x;
    for (int i = tid; i < 3 * C1 * C1; i += 512) {
        int tap = i / (C1 * C1), rem = i % (C1 * C1), f = rem / C1, j = rem % C1;
        WI[((tap * 16 + (f >> 2)) * 64 + j) * 4 + (f & 3)] = W2[i];
    }
    for (int i = tid; i < C1 * OUTF; i += 512) {
        int j = i / OUTF, o = i % OUTF;
        LWT[i] = linW[o * C1 + j];
    }
    __syncthreads();

    const int lane = tid & 63;
    const int wv   = tid >> 6;
    const int gw   = blockIdx.x * 8 + wv;
    const int rstep = gridDim.x * 8 * 4;
    const float bias = b2[lane];
    const float lb   = linb[lane & 15];
    const int rsel = lane >> 4, osel = lane & 15;
    const float4* W4 = (const float4*)WI;
    const float4* R4 = (const float4*)ROWS;
    float* gb = &ROWS[wv * (4 * 3 * 64)];   // per-wave gbuf: 4 rows x 72 <= 768 floats

    for (int r0 = gw * 4; r0 < n; r0 += rstep) {
        const int nr = min(4, n - r0);
        #pragma unroll
        for (int r = 0; r < 4; ++r) {
            int row = min(r0 + r, n - 1);
            ROWS[((wv * 4 + r) * 3 + 0) * 64 + lane] = hb[row * C1 + lane];
            ROWS[((wv * 4 + r) * 3 + 1) * 64 + lane] = Q1[row * C1 + lane];
            ROWS[((wv * 4 + r) * 3 + 2) * 64 + lane] = T2[row * C1 + lane];
        }
        float acc[4] = {bias, bias, bias, bias};
        for (int c = 0; c < 16; ++c) {
            float4 w0 = W4[(0 * 16 + c) * 64 + lane];
            float4 w1 = W4[(1 * 16 + c) * 64 + lane];
            float4 w2 = W4[(2 * 16 + c) * 64 + lane];
            #pragma unroll
            for (int r = 0; r < 4; ++r) {
                float4 t0 = R4[((wv * 4 + r) * 3 + 0) * 16 + c];   // broadcast
                float4 t1 = R4[((wv * 4 + r) * 3 + 1) * 16 + c];
                float4 t2 = R4[((wv * 4 + r) * 3 + 2) * 16 + c];
                acc[r] += t0.x * w0.x + t0.y * w0.y + t0.z * w0.z + t0.w * w0.w
                        + t1.x * w1.x + t1.y * w1.y + t1.z * w1.z + t1.w * w1.w
                        + t2.x * w2.x + t2.y * w2.y + t2.z * w2.z + t2.w * w2.w;
            }
        }
        // rows consumed; reuse this wave's ROWS slice as gbuf (same-wave DS in-order)
        #pragma unroll
        for (int r = 0; r < 4; ++r)
            gb[r * 72 + lane] = (r < nr) ? fmaxf(acc[r], 0.f) : 0.f;
        float oa = lb;
        #pragma unroll 8
        for (int j = 0; j < C1; ++j)
            oa += gb[rsel * 72 + j] * LWT[j * OUTF + osel];
        int rw = r0 + rsel;
        if (rw < n) out[rw * OUTF + osel] = oa;   // contiguous 256B store per wave
    }
}

// ---------------------------------------------------------------- launch
extern "C" void kernel_launch(void* const* d_in, const int* in_sizes, int n_in,
                              void* d_out, int out_size, void* d_ws, size_t ws_size,
                              hipStream_t stream)
{
    const float* x     = (const float*)d_in[0];
    const int*   ei    = (const int*)  d_in[1];
    const float* ew    = (const float*)d_in[2];
    const float* W1    = (const float*)d_in[3];
    const float* b1    = (const float*)d_in[4];
    const float* W2    = (const float*)d_in[5];
    const float* b2    = (const float*)d_in[6];
    const float* gamma = (const float*)d_in[7];
    const float* beta  = (const float*)d_in[8];
    const float* linW  = (const float*)d_in[9];
    const float* linb  = (const float*)d_in[10];
    float* out = (float*)d_out;
    (void)n_in; (void)out_size; (void)ws_size;

    const int n = in_sizes[0] / NF;    // 100000
    const int e = in_sizes[2];         // 1600000
    const int* row = ei;
    const int* col = ei + e;

    char* ws = (char*)d_ws;
    size_t off = 0;
    auto alloc = [&](size_t bytes) -> void* {
        void* p = ws + off;
        off += (bytes + 255) & ~(size_t)255;
        return p;
    };
    unsigned long long* pcd = (unsigned long long*)alloc((size_t)n * 8);
    float* dis    = (float*)alloc((size_t)n * 4);
    int*   cnt    = (int*)  alloc((size_t)n * 4);
    int*   rowptr = (int*)  alloc((size_t)n * 4);
    int*   rank   = (int*)  alloc((size_t)e * 4);
    int*   bsum   = (int*)  alloc(256 * 4);
    float* stats  = (float*)alloc(256 * 4);         // [sum|sumsq|scale|shift] x 64
    int2*  ecn    = (int2*) alloc((size_t)e * 8);   // interleaved (col, norm)
    float* X64    = (float*)alloc((size_t)n * C1 * 4);   // padded x (stride 64)
    float* U      = (float*)alloc((size_t)n * C1 * 4);   // T1, then h/hb (in-place)
    float* H      = (float*)alloc((size_t)n * C1 * 4);   // T2, then Q1
    float* S      = (float*)alloc((size_t)n * C1 * 4);   // T2' (conv2)

    hipMemsetAsync(pcd,   0, (size_t)n * 8, stream);
    hipMemsetAsync(stats, 0, 256 * 4, stream);

    const int eb  = (e + 255) / 256;
    const int nbk = (n + 255) / 256;
    pass1_kernel<<<eb, 256, 0, stream>>>(row, ew, pcd, rank, e);
    dis_kernel<<<nbk, 256, 0, stream>>>(pcd, dis, cnt, n);
    padx_kernel<<<(n * 16 + 255) / 256, 256, 0, stream>>>(x, (float4*)X64, n * 16);

    const int nb = (n + SCAN_T * SCAN_I - 1) / (SCAN_T * SCAN_I);   // 98 <= 256
    scan_partial<<<nb, SCAN_T, 0, stream>>>(cnt, bsum, n);
    scan_bsums<<<1, 256, 0, stream>>>(bsum, nb);
    scan_final<<<nb, SCAN_T, 0, stream>>>(cnt, bsum, rowptr, n);
    scatter_kernel<<<eb, 256, 0, stream>>>(row, col, ew, dis, rowptr, rank, ecn, e);

    const int pb = (n + 3) / 4;   // one wave per row, 4 waves/block

    // conv1: T1 = prop(X64) -> U; T2 = 2*prop(T1) - X64 -> H; h = relu(dense) in-place U (+BN)
    prop_kernel<0><<<pb, 256, 0, stream>>>(X64, X64, rowptr, cnt, ecn, U, n);
    prop_kernel<1><<<pb, 256, 0, stream>>>(U, X64, rowptr, cnt, ecn, H, n);
    dense1_kernel<<<1024, 512, 0, stream>>>(x, U, H, W1, b1, stats, n);
    bn_finalize_kernel<<<1, 64, 0, stream>>>(stats, gamma, beta, 1.f / (float)n);
    bn_apply_kernel<<<2048, 256, 0, stream>>>(U, stats, n * C1 / 4);

    // conv2: Q1 = prop(hb) -> H; T2' = 2*prop(Q1) - hb -> S; out = dense+linear
    prop_kernel<0><<<pb, 256, 0, stream>>>(U, U, rowptr, cnt, ecn, H, n);
    prop_kernel<1><<<pb, 256, 0, stream>>>(H, U, rowptr, cnt, ecn, S, n);
    dense2_kernel<<<1024, 512, 0, stream>>>(U, H, S, W2, b2, linW, linb, out, n);
}

// Round 14
// 518.327 us; speedup vs baseline: 1.1692x; 1.1692x over previous
//
#include <hip/hip_runtime.h>
#include <hip/hip_bf16.h>
#include <hip/hip_fp16.h>

static constexpr int NF   = 50;   // input features
static constexpr int C1   = 64;   // conv1/conv2 channels
static constexpr int OUTF = 16;   // final output features
static constexpr int SCAN_T = 256;
static constexpr int SCAN_I = 4;
static constexpr float DEG_SCALE   = 8388608.f;      // 2^23 fixed-point for packed deg
static constexpr float DEG_INV     = 1.f / 8388608.f;

// ---------------------------------------------------------------- CSR build
// ONE packed 64-bit atomic per edge: high word = edge count, low word = fixed-point
// weighted degree. Returned old high word = this edge's rank within its row.
__global__ void pass1_kernel(const int* __restrict__ row, const float* __restrict__ w,
                             unsigned long long* __restrict__ pcd, int* __restrict__ rank, int e)
{
    int i = blockIdx.x * blockDim.x + threadIdx.x;
    if (i < e) {
        int r = row[i];
        unsigned int wq = (unsigned int)(w[i] * DEG_SCALE + 0.5f);
        unsigned long long pk = (1ULL << 32) | (unsigned long long)wq;
        unsigned long long old = atomicAdd(&pcd[r], pk);
        rank[i] = (int)(old >> 32);
    }
}

__global__ void dis_kernel(const unsigned long long* __restrict__ pcd,
                           float* __restrict__ dis, int* __restrict__ cnt, int n)
{
    int i = blockIdx.x * blockDim.x + threadIdx.x;
    if (i < n) {
        unsigned long long pk = pcd[i];
        int c = (int)(pk >> 32);
        float d = (float)(unsigned int)(pk & 0xFFFFFFFFu) * DEG_INV;
        cnt[i] = c;
        dis[i] = (d > 0.f) ? (1.f / sqrtf(d)) : 0.f;
    }
}

__global__ void scan_partial(const int* __restrict__ cnt, int* __restrict__ bsum, int n)
{
    __shared__ int sm[SCAN_T];
    int t = threadIdx.x;
    int base = blockIdx.x * SCAN_T * SCAN_I + t * SCAN_I;
    int s = 0;
    #pragma unroll
    for (int k = 0; k < SCAN_I; ++k) { int i = base + k; if (i < n) s += cnt[i]; }
    sm[t] = s; __syncthreads();
    for (int off = SCAN_T / 2; off > 0; off >>= 1) {
        if (t < off) sm[t] += sm[t + off];
        __syncthreads();
    }
    if (t == 0) bsum[blockIdx.x] = sm[0];
}

// single block; requires nb <= 256 (here nb = 98)
__global__ void scan_bsums(int* __restrict__ bsum, int nb)
{
    __shared__ int sm[256];
    int t = threadIdx.x;
    sm[t] = (t < nb) ? bsum[t] : 0;
    __syncthreads();
    for (int off = 1; off < 256; off <<= 1) {
        int v = (t >= off) ? sm[t - off] : 0;
        __syncthreads();
        sm[t] += v;
        __syncthreads();
    }
    if (t < nb) bsum[t] = (t == 0) ? 0 : sm[t - 1];   // exclusive
}

__global__ void scan_final(const int* __restrict__ cnt, const int* __restrict__ bsum,
                           int* __restrict__ rowptr, int n)
{
    __shared__ int sm[SCAN_T];
    int t = threadIdx.x;
    int base = blockIdx.x * SCAN_T * SCAN_I + t * SCAN_I;
    int v[SCAN_I]; int s = 0;
    #pragma unroll
    for (int k = 0; k < SCAN_I; ++k) { int i = base + k; v[k] = (i < n) ? cnt[i] : 0; s += v[k]; }
    sm[t] = s; __syncthreads();
    for (int off = 1; off < SCAN_T; off <<= 1) {
        int x = (t >= off) ? sm[t - off] : 0;
        __syncthreads();
        sm[t] += x;
        __syncthreads();
    }
    int pref = bsum[blockIdx.x] + sm[t] - s;   // thread-exclusive prefix
    #pragma unroll
    for (int k = 0; k < SCAN_I; ++k) {
        int i = base + k;
        if (i < n) { rowptr[i] = pref; pref += v[k]; }
    }
}

// atomic-free scatter: pos = rowptr[row] + rank. Writes interleaved (col, norm) int2.
__global__ void scatter_kernel(const int* __restrict__ row, const int* __restrict__ col,
                               const float* __restrict__ w, const float* __restrict__ dis,
                               const int* __restrict__ rowptr, const int* __restrict__ rank,
                               int2* __restrict__ ecn, int e)
{
    int i = blockIdx.x * blockDim.x + threadIdx.x;
    if (i < e) {
        int r = row[i], c = col[i];
        int pos = rowptr[r] + rank[i];
        float nv = -dis[r] * w[i] * dis[c];
        ecn[pos] = make_int2(c, __float_as_int(nv));
    }
}

// pad x [n][50] -> XH [n][64] fp16 (zeros beyond 50): gather tables are half the bytes
__global__ void padx_kernel(const float* __restrict__ x, __half* __restrict__ XH, int n64)
{
    int i = blockIdx.x * blockDim.x + threadIdx.x;
    if (i < n64) {
        int row = i >> 6, f = i & 63;
        XH[i] = __float2half((f < NF) ? x[row * NF + f] : 0.f);
    }
}

// ---------------------------------------------------------------- propagate (pure gather)
// One wave per row, lane = feature, ZERO LDS. Gather table is fp16 (128B/row on the
// fabric, half of fp32); accumulate fp32; write fp32 result (+ fp16 shadow if a later
// prop gathers it). Masked unroll-8 (R11's measured-best scalar structure).
// BS: base stride for fused T2 = 2*acc - base (0 = off; 50 = x masked; 64 = full).
template<int BS, bool SHADOW>
__global__ __launch_bounds__(256) void prop_kernel(
    const __half* __restrict__ xin, const float* __restrict__ base,
    const int* __restrict__ rowptr, const int* __restrict__ cnt,
    const int2* __restrict__ ecn, float* __restrict__ yout,
    __half* __restrict__ ysh, int n)
{
    int gw = (blockIdx.x * blockDim.x + threadIdx.x) >> 6;
    int lane = threadIdx.x & 63;
    if (gw >= n) return;
    int st = __builtin_amdgcn_readfirstlane(rowptr[gw]);
    int m  = __builtin_amdgcn_readfirstlane(cnt[gw]);
    float a[8] = {0.f, 0.f, 0.f, 0.f, 0.f, 0.f, 0.f, 0.f};
    for (int t = 0; t < m; t += 8) {
        #pragma unroll
        for (int k = 0; k < 8; ++k) {
            int tk = t + k;
            int idx = st + min(tk, m - 1);             // clamped: valid when m>=1
            int2 md = ecn[idx];
            float nv = (tk < m) ? __int_as_float(md.y) : 0.f;
            a[k] += nv * __half2float(xin[md.x * C1 + lane]);
        }
    }
    float acc = ((a[0] + a[1]) + (a[2] + a[3])) + ((a[4] + a[5]) + (a[6] + a[7]));
    if (BS > 0) {   // T2 = 2*prop - base  (m==0: -base, correct)
        float bv = (BS == C1 || lane < BS) ? base[(size_t)gw * BS + lane] : 0.f;
        acc = 2.f * acc - bv;
    }
    yout[(size_t)gw * C1 + lane] = acc;
    if (SHADOW) ysh[(size_t)gw * C1 + lane] = __float2half(acc);
}

// ---------------------------------------------------------------- dense conv1 (+BN stats)
// h = relu(x@W0 + T1@W1 + T2@W2 + b1); h IN PLACE over T1 (row-local).
// Measured-best structure (R9): W in LDS [tap][f/4][j][4]; rows staged coalesced in
// per-wave LDS, read back as same-address b128 broadcasts. All fp32.
__global__ __launch_bounds__(512) void dense1_kernel(
    const float* __restrict__ x, float* U /*T1 in, h out*/, const float* __restrict__ T2,
    const float* __restrict__ W1, const float* __restrict__ b1,
    float* __restrict__ stats, int n)
{
    __shared__ __align__(16) float WI[3 * 13 * 64 * 4];   // 39936 B
    __shared__ __align__(16) float ROWS[8 * 4 * 3 * 64];  // 24576 B
    __shared__ float red[2][8][64];                       // 4 KB
    const int tid = threadIdx.x;
    for (int i = tid; i < 3 * 13 * 64 * 4; i += 512) WI[i] = 0.f;
    __syncthreads();
    for (int i = tid; i < 3 * NF * C1; i += 512) {
        int tap = i / (NF * C1), rem = i % (NF * C1), f = rem / C1, j = rem % C1;
        WI[((tap * 13 + (f >> 2)) * 64 + j) * 4 + (f & 3)] = W1[i];
    }
    __syncthreads();

    const int lane = tid & 63;
    const int wv   = tid >> 6;
    const int gw   = blockIdx.x * 8 + wv;
    const int rstep = gridDim.x * 8 * 4;
    const float bias = b1[lane];
    const float4* W4 = (const float4*)WI;
    const float4* R4 = (const float4*)ROWS;
    float ssum = 0.f, ssq = 0.f;

    for (int r0 = gw * 4; r0 < n; r0 += rstep) {
        const int nr = min(4, n - r0);
        // stage this wave's 4 rows x 3 tables (coalesced); same-wave use, no barrier
        #pragma unroll
        for (int r = 0; r < 4; ++r) {
            int row = min(r0 + r, n - 1);
            ROWS[((wv * 4 + r) * 3 + 0) * 64 + lane] = (lane < NF) ? x[row * NF + lane] : 0.f;
            ROWS[((wv * 4 + r) * 3 + 1) * 64 + lane] = U [row * C1 + lane];
            ROWS[((wv * 4 + r) * 3 + 2) * 64 + lane] = T2[row * C1 + lane];
        }
        float acc[4] = {bias, bias, bias, bias};
        for (int c = 0; c < 13; ++c) {
            float4 w0 = W4[(0 * 13 + c) * 64 + lane];
            float4 w1 = W4[(1 * 13 + c) * 64 + lane];
            float4 w2 = W4[(2 * 13 + c) * 64 + lane];
            #pragma unroll
            for (int r = 0; r < 4; ++r) {
                float4 t0 = R4[((wv * 4 + r) * 3 + 0) * 16 + c];   // broadcast
                float4 t1 = R4[((wv * 4 + r) * 3 + 1) * 16 + c];
                float4 t2 = R4[((wv * 4 + r) * 3 + 2) * 16 + c];
                acc[r] += t0.x * w0.x + t0.y * w0.y + t0.z * w0.z + t0.w * w0.w
                        + t1.x * w1.x + t1.y * w1.y + t1.z * w1.z + t1.w * w1.w
                        + t2.x * w2.x + t2.y * w2.y + t2.z * w2.z + t2.w * w2.w;
            }
        }
        #pragma unroll
        for (int r = 0; r < 4; ++r) {
            if (r < nr) {
                float v = fmaxf(acc[r], 0.f);
                U[(r0 + r) * C1 + lane] = v;       // in-place: own rows only
                ssum += v; ssq += v * v;
            }
        }
    }
    red[0][wv][lane] = ssum;
    red[1][wv][lane] = ssq;
    __syncthreads();
    if (tid < 128) {
        int which = tid >> 6, j = tid & 63;
        float tot = 0.f;
        #pragma unroll
        for (int wq = 0; wq < 8; ++wq) tot += red[which][wq][j];
        atomicAdd(&stats[which * 64 + j], tot);
    }
}

// ---------------------------------------------------------------- batch norm
__global__ void bn_finalize_kernel(float* __restrict__ stats, const float* __restrict__ gamma,
                                   const float* __restrict__ beta, float inv_n)
{
    int j = threadIdx.x;
    if (j < 64) {
        float mu   = stats[j] * inv_n;
        float var  = stats[64 + j] * inv_n - mu * mu;
        float rstd = 1.f / sqrtf(var + 1e-5f);
        float sc   = gamma[j] * rstd;
        stats[128 + j] = sc;
        stats[192 + j] = beta[j] - mu * sc;
    }
}

// BN in-place on fp32 h; also emits the fp16 shadow HH for conv2's gathers.
__global__ void bn_apply_kernel(float* __restrict__ h, __half2* __restrict__ hh,
                                const float* __restrict__ stats, int n4)
{
    int i = blockIdx.x * blockDim.x + threadIdx.x;
    const int stride = gridDim.x * blockDim.x;      // multiple of 16 -> j0 invariant
    int j0 = (i * 4) & 63;
    float s0 = stats[128 + j0], s1 = stats[129 + j0], s2 = stats[130 + j0], s3 = stats[131 + j0];
    float b0 = stats[192 + j0], b1 = stats[193 + j0], b2 = stats[194 + j0], b3 = stats[195 + j0];
    float4* h4 = (float4*)h;
    for (; i < n4; i += stride) {
        float4 v = h4[i];
        v.x = v.x * s0 + b0;
        v.y = v.y * s1 + b1;
        v.z = v.z * s2 + b2;
        v.w = v.w * s3 + b3;
        h4[i] = v;
        hh[i * 2 + 0] = __floats2half2_rn(v.x, v.y);
        hh[i * 2 + 1] = __floats2half2_rn(v.z, v.w);
    }
}

// ---------------------------------------------------------------- dense conv2 + final linear
// g = relu(hb@W0 + Q1@W1 + T2'@W2 + b2);  out = g @ linW^T + linb   (all fp32)
__global__ __launch_bounds__(512) void dense2_kernel(
    const float* __restrict__ hb, const float* __restrict__ Q1, const float* __restrict__ T2,
    const float* __restrict__ W2, const float* __restrict__ b2,
    const float* __restrict__ linW, const float* __restrict__ linb,
    float* __restrict__ out, int n)
{
    __shared__ __align__(16) float WI[3 * 16 * 64 * 4];   // 49152 B
    __shared__ __align__(16) float ROWS[8 * 4 * 3 * 64];  // 24576 B (gbuf reuses per-wave slice)
    __shared__ float LWT[C1 * OUTF];                      // 4 KB, [j][o]
    const int tid = threadIdx.x;
    for (int i = tid; i < 3 * C1 * C1; i += 512) {
        int tap = i / (C1 * C1), rem = i % (C1 * C1), f = rem / C1, j = rem % C1;
        WI[((tap * 16 + (f >> 2)) * 64 + j) * 4 + (f & 3)] = W2[i];
    }
    for (int i = tid; i < C1 * OUTF; i += 512) {
        int j = i / OUTF, o = i % OUTF;
        LWT[i] = linW[o * C1 + j];
    }
    __syncthreads();

    const int lane = tid & 63;
    const int wv   = tid >> 6;
    const int gw   = blockIdx.x * 8 + wv;
    const int rstep = gridDim.x * 8 * 4;
    const float bias = b2[lane];
    const float lb   = linb[lane & 15];
    const int rsel = lane >> 4, osel = lane & 15;
    const float4* W4 = (const float4*)WI;
    const float4* R4 = (const float4*)ROWS;
    float* gb = &ROWS[wv * (4 * 3 * 64)];   // per-wave gbuf: 4 rows x 72 <= 768 floats

    for (int r0 = gw * 4; r0 < n; r0 += rstep) {
        const int nr = min(4, n - r0);
        #pragma unroll
        for (int r = 0; r < 4; ++r) {
            int row = min(r0 + r, n - 1);
            ROWS[((wv * 4 + r) * 3 + 0) * 64 + lane] = hb[row * C1 + lane];
            ROWS[((wv * 4 + r) * 3 + 1) * 64 + lane] = Q1[row * C1 + lane];
            ROWS[((wv * 4 + r) * 3 + 2) * 64 + lane] = T2[row * C1 + lane];
        }
        float acc[4] = {bias, bias, bias, bias};
        for (int c = 0; c < 16; ++c) {
            float4 w0 = W4[(0 * 16 + c) * 64 + lane];
            float4 w1 = W4[(1 * 16 + c) * 64 + lane];
            float4 w2 = W4[(2 * 16 + c) * 64 + lane];
            #pragma unroll
            for (int r = 0; r < 4; ++r) {
                float4 t0 = R4[((wv * 4 + r) * 3 + 0) * 16 + c];   // broadcast
                float4 t1 = R4[((wv * 4 + r) * 3 + 1) * 16 + c];
                float4 t2 = R4[((wv * 4 + r) * 3 + 2) * 16 + c];
                acc[r] += t0.x * w0.x + t0.y * w0.y + t0.z * w0.z + t0.w * w0.w
                        + t1.x * w1.x + t1.y * w1.y + t1.z * w1.z + t1.w * w1.w
                        + t2.x * w2.x + t2.y * w2.y + t2.z * w2.z + t2.w * w2.w;
            }
        }
        // rows consumed; reuse this wave's ROWS slice as gbuf (same-wave DS in-order)
        #pragma unroll
        for (int r = 0; r < 4; ++r)
            gb[r * 72 + lane] = (r < nr) ? fmaxf(acc[r], 0.f) : 0.f;
        float oa = lb;
        #pragma unroll 8
        for (int j = 0; j < C1; ++j)
            oa += gb[rsel * 72 + j] * LWT[j * OUTF + osel];
        int rw = r0 + rsel;
        if (rw < n) out[rw * OUTF + osel] = oa;   // contiguous 256B store per wave
    }
}

// ---------------------------------------------------------------- launch
extern "C" void kernel_launch(void* const* d_in, const int* in_sizes, int n_in,
                              void* d_out, int out_size, void* d_ws, size_t ws_size,
                              hipStream_t stream)
{
    const float* x     = (const float*)d_in[0];
    const int*   ei    = (const int*)  d_in[1];
    const float* ew    = (const float*)d_in[2];
    const float* W1    = (const float*)d_in[3];
    const float* b1    = (const float*)d_in[4];
    const float* W2    = (const float*)d_in[5];
    const float* b2    = (const float*)d_in[6];
    const float* gamma = (const float*)d_in[7];
    const float* beta  = (const float*)d_in[8];
    const float* linW  = (const float*)d_in[9];
    const float* linb  = (const float*)d_in[10];
    float* out = (float*)d_out;
    (void)n_in; (void)out_size; (void)ws_size;

    const int n = in_sizes[0] / NF;    // 100000
    const int e = in_sizes[2];         // 1600000
    const int* row = ei;
    const int* col = ei + e;

    char* ws = (char*)d_ws;
    size_t off = 0;
    auto alloc = [&](size_t bytes) -> void* {
        void* p = ws + off;
        off += (bytes + 255) & ~(size_t)255;
        return p;
    };
    unsigned long long* pcd = (unsigned long long*)alloc((size_t)n * 8);
    float*  dis    = (float*)alloc((size_t)n * 4);
    int*    cnt    = (int*)  alloc((size_t)n * 4);
    int*    rowptr = (int*)  alloc((size_t)n * 4);
    int*    rank   = (int*)  alloc((size_t)e * 4);
    int*    bsum   = (int*)  alloc(256 * 4);
    float*  stats  = (float*)alloc(256 * 4);        // [sum|sumsq|scale|shift] x 64
    int2*   ecn    = (int2*) alloc((size_t)e * 8);  // interleaved (col, norm)
    __half* XH     = (__half*)alloc((size_t)n * C1 * 2);   // fp16 padded x
    __half* T1H    = (__half*)alloc((size_t)n * C1 * 2);   // fp16 shadow of T1
    __half* HH     = (__half*)alloc((size_t)n * C1 * 2);   // fp16 shadow of hb
    __half* Q1H    = (__half*)alloc((size_t)n * C1 * 2);   // fp16 shadow of Q1
    float*  U      = (float*)alloc((size_t)n * C1 * 4);    // T1, then h/hb (in-place)
    float*  H      = (float*)alloc((size_t)n * C1 * 4);    // T2, then Q1
    float*  S      = (float*)alloc((size_t)n * C1 * 4);    // T2' (conv2)

    hipMemsetAsync(pcd,   0, (size_t)n * 8, stream);
    hipMemsetAsync(stats, 0, 256 * 4, stream);

    const int eb  = (e + 255) / 256;
    const int nbk = (n + 255) / 256;
    pass1_kernel<<<eb, 256, 0, stream>>>(row, ew, pcd, rank, e);
    dis_kernel<<<nbk, 256, 0, stream>>>(pcd, dis, cnt, n);
    padx_kernel<<<(n * C1 + 255) / 256, 256, 0, stream>>>(x, XH, n * C1);

    const int nb = (n + SCAN_T * SCAN_I - 1) / (SCAN_T * SCAN_I);   // 98 <= 256
    scan_partial<<<nb, SCAN_T, 0, stream>>>(cnt, bsum, n);
    scan_bsums<<<1, 256, 0, stream>>>(bsum, nb);
    scan_final<<<nb, SCAN_T, 0, stream>>>(cnt, bsum, rowptr, n);
    scatter_kernel<<<eb, 256, 0, stream>>>(row, col, ew, dis, rowptr, rank, ecn, e);

    const int pb = (n + 3) / 4;   // one wave per row, 4 waves/block

    // conv1: T1 = prop(XH) -> U (+T1H); T2 = 2*prop(T1H) - x -> H; h = relu(dense) in U (+BN)
    prop_kernel<0,  true ><<<pb, 256, 0, stream>>>(XH,  x, rowptr, cnt, ecn, U, T1H, n);
    prop_kernel<NF, false><<<pb, 256, 0, stream>>>(T1H, x, rowptr, cnt, ecn, H, T1H, n);
    dense1_kernel<<<1024, 512, 0, stream>>>(x, U, H, W1, b1, stats, n);
    bn_finalize_kernel<<<1, 64, 0, stream>>>(stats, gamma, beta, 1.f / (float)n);
    bn_apply_kernel<<<2048, 256, 0, stream>>>(U, (__half2*)HH, stats, n * C1 / 4);

    // conv2: Q1 = prop(HH) -> H (+Q1H); T2' = 2*prop(Q1H) - hb -> S; out = dense+linear
    prop_kernel<0,  true ><<<pb, 256, 0, stream>>>(HH,  U, rowptr, cnt, ecn, H, Q1H, n);
    prop_kernel<C1, false><<<pb, 256, 0, stream>>>(Q1H, U, rowptr, cnt, ecn, S, Q1H, n);
    dense2_kernel<<<1024, 512, 0, stream>>>(U, H, S, W2, b2, linW, linb, out, n);
}